// Round 6
// baseline (28.261 us; speedup 1.0000x reference)
//
#include <hip/hip_runtime.h>

#define SEQ 256
#define NENV 64
#define NGROUPS 12
#define GDIM 128
#define ROWS (SEQ * NENV)           // 16384
#define HALFROWS (ROWS / 2)         // 8192
#define WPB 4                       // waves per block -> 256 threads
#define NBLOCKS (HALFROWS / WPB)    // 2048

// Kernel 1: latency-minimal fold. Block d computes v[d] = Wg[d,:] . Wa[128:].
__global__ __launch_bounds__(64)
void fold_v(const float* __restrict__ Wg,
            const float* __restrict__ Wa,
            float* __restrict__ v) {
    const int d    = blockIdx.x;
    const int lane = threadIdx.x;
    const float2 r = *reinterpret_cast<const float2*>(Wg + d * 128 + 2 * lane);
    const float2 w = *reinterpret_cast<const float2*>(Wa + 128 + 2 * lane);
    float p = r.x * w.x + r.y * w.y;
    p += __shfl_xor(p, 1);
    p += __shfl_xor(p, 2);
    p += __shfl_xor(p, 4);
    p += __shfl_xor(p, 8);
    p += __shfl_xor(p, 16);
    p += __shfl_xor(p, 32);
    if (lane == 0) v[d] = p;
}

// One R1-exact row body, operating on preloaded registers g[6].
__device__ __forceinline__ void row_body(const float4 (&g)[6],
                                         const float4& vf,
                                         int lane, int half, int l32, int row,
                                         float* __restrict__ out_weighted,
                                         float* __restrict__ out_weights) {
    float sc[12];
#pragma unroll
    for (int t = 0; t < 6; ++t) {
        float p = g[t].x * vf.x + g[t].y * vf.y + g[t].z * vf.z + g[t].w * vf.w;
        p += __shfl_xor(p, 1);
        p += __shfl_xor(p, 2);
        p += __shfl_xor(p, 4);
        p += __shfl_xor(p, 8);
        p += __shfl_xor(p, 16);
        float q = __shfl_xor(p, 32);
        sc[2 * t]     = half ? q : p;
        sc[2 * t + 1] = half ? p : q;
    }

    float m = sc[0];
#pragma unroll
    for (int i = 1; i < NGROUPS; ++i) m = fmaxf(m, sc[i]);
    float w[12];
    float sum = 0.0f;
#pragma unroll
    for (int i = 0; i < NGROUPS; ++i) {
        w[i] = __expf(sc[i] - m);
        sum += w[i];
    }
    const float inv = 1.0f / sum;
#pragma unroll
    for (int i = 0; i < NGROUPS; ++i) w[i] *= inv;

    float4 acc = make_float4(0.f, 0.f, 0.f, 0.f);
#pragma unroll
    for (int t = 0; t < 6; ++t) {
        const float wt = w[2 * t + half];
        acc.x += wt * g[t].x;
        acc.y += wt * g[t].y;
        acc.z += wt * g[t].z;
        acc.w += wt * g[t].w;
    }
    acc.x += __shfl_xor(acc.x, 32);
    acc.y += __shfl_xor(acc.y, 32);
    acc.z += __shfl_xor(acc.z, 32);
    acc.w += __shfl_xor(acc.w, 32);

    if (lane < 32) {
        *reinterpret_cast<float4*>(out_weighted + (size_t)row * GDIM + l32 * 4) = acc;
    } else if (lane < 32 + NGROUPS) {
        out_weights[(size_t)row * NGROUPS + (lane - 32)] = w[lane - 32];
    }
}

// Kernel 2: one wave per TWO independent rows (rowA = id, rowB = id + 8192).
// All 12 loads issue up front (12KB MLP/wave); two sequential R1-exact bodies.
__global__ __launch_bounds__(WPB * 64)
void group_attn(const float* __restrict__ ge,     // (ROWS, 12, 128)
                const float* __restrict__ v,      // (128)
                float* __restrict__ out_weighted, // (ROWS, 128)
                float* __restrict__ out_weights)  // (ROWS, 12)
{
    const int wave = threadIdx.x >> 6;
    const int lane = threadIdx.x & 63;
    const int rowA = blockIdx.x * WPB + wave;
    const int rowB = rowA + HALFROWS;

    const int half = lane >> 5;
    const int l32  = lane & 31;

    const float* baseA = ge + (size_t)rowA * (NGROUPS * GDIM) + lane * 4;
    const float* baseB = ge + (size_t)rowB * (NGROUPS * GDIM) + lane * 4;

    // Issue all 12 row loads before any compute.
    float4 gA[6], gB[6];
#pragma unroll
    for (int t = 0; t < 6; ++t)
        gA[t] = *reinterpret_cast<const float4*>(baseA + t * 256);
#pragma unroll
    for (int t = 0; t < 6; ++t)
        gB[t] = *reinterpret_cast<const float4*>(baseB + t * 256);

    const float4 vf = *reinterpret_cast<const float4*>(v + l32 * 4);

    row_body(gA, vf, lane, half, l32, rowA, out_weighted, out_weights);
    row_body(gB, vf, lane, half, l32, rowB, out_weighted, out_weights);
}

extern "C" void kernel_launch(void* const* d_in, const int* in_sizes, int n_in,
                              void* d_out, int out_size, void* d_ws, size_t ws_size,
                              hipStream_t stream) {
    // Inputs: 0 robot_states (unused) 1 group_embeddings 2 Wr (unused)
    // 3 br (unused) 4 Wg 5 bg (unused) 6 Wa 7 ba (unused)
    const float* ge = (const float*)d_in[1];
    const float* Wg = (const float*)d_in[4];
    const float* Wa = (const float*)d_in[6];

    float* v = (float*)d_ws;                                   // 128 floats
    float* out_weighted = (float*)d_out;                       // ROWS*128
    float* out_weights  = out_weighted + (size_t)ROWS * GDIM;  // ROWS*12

    fold_v<<<GDIM, 64, 0, stream>>>(Wg, Wa, v);
    group_attn<<<NBLOCKS, WPB * 64, 0, stream>>>(
        ge, v, out_weighted, out_weights);
}

// Round 7
// 23.662 us; speedup vs baseline: 1.1944x; 1.1944x over previous
//
#include <hip/hip_runtime.h>

#define SEQ 256
#define NENV 64
#define NGROUPS 12
#define GDIM 128
#define ROWS (SEQ * NENV)           // 16384
#define TPB 1024                    // 16 waves per block
#define WPB 16                      // waves (= rows) per block
#define NBLOCKS (ROWS / WPB)        // 1024

// Single fused kernel.
// Phase A (per wave): issue the 6 ge row loads (independent of v).
// Phase B (per block): coalesced fold v = Wg @ Wa[128:256] into LDS.
//   - thread tid reads float4 quads {tid + 1024k}, k=0..3 (1KB/instr, coalesced)
//   - quad q belongs to row q/32, col-quad q%32 == tid%32 (constant/thread)
//   - two-stage LDS reduce: 32 quad-partials -> v[d]
// Phase C (per wave): R1-verbatim row body using vf from LDS.
__global__ __launch_bounds__(TPB, 8)
void group_attn_fused(const float* __restrict__ ge,     // (ROWS, 12, 128)
                      const float* __restrict__ Wg,     // (128, 128)
                      const float* __restrict__ Wa,     // (256, 1)
                      float* __restrict__ out_weighted, // (ROWS, 128)
                      float* __restrict__ out_weights)  // (ROWS, 12)
{
    __shared__ float p1[4096];      // quad partials (16 KB)
    __shared__ float p2[8][128];    // stage-2 partials (4 KB)
    __shared__ float v_lds[GDIM];

    const int tid  = threadIdx.x;
    const int wave = tid >> 6;
    const int lane = tid & 63;
    const int row  = blockIdx.x * WPB + wave;
    const int half = lane >> 5;     // 0: even groups, 1: odd groups
    const int l32  = lane & 31;     // dims [l32*4, l32*4+3]

    // ---- Phase A: issue ge loads first; latency hides under the fold.
    const float* base = ge + (size_t)row * (NGROUPS * GDIM) + lane * 4;
    float4 g[6];
#pragma unroll
    for (int t = 0; t < 6; ++t)
        g[t] = *reinterpret_cast<const float4*>(base + t * 256);

    // ---- Phase B: fold prologue (coalesced).
    {
        const float4* wg4 = reinterpret_cast<const float4*>(Wg);     // 4096 quads
        const float4  waf = reinterpret_cast<const float4*>(Wa + 128)[tid & 31];
#pragma unroll
        for (int k = 0; k < 4; ++k) {
            const int q = tid + TPB * k;
            const float4 f = wg4[q];
            p1[q] = f.x * waf.x + f.y * waf.y + f.z * waf.z + f.w * waf.w;
        }
    }
    __syncthreads();
    {
        // 8 threads per output dim d: each sums 4 quad-partials (one b128 read).
        const int d = tid >> 3, oct = tid & 7;
        const float4 r = *reinterpret_cast<const float4*>(&p1[d * 32 + oct * 4]);
        p2[oct][d] = r.x + r.y + r.z + r.w;
    }
    __syncthreads();
    if (tid < GDIM) {
        float s = 0.0f;
#pragma unroll
        for (int o = 0; o < 8; ++o) s += p2[o][tid];
        v_lds[tid] = s;
    }
    __syncthreads();

    const float4 vf = *reinterpret_cast<const float4*>(&v_lds[l32 * 4]);

    // ---- Phase C: R1-verbatim row body.
    float sc[12];
#pragma unroll
    for (int t = 0; t < 6; ++t) {
        float p = g[t].x * vf.x + g[t].y * vf.y + g[t].z * vf.z + g[t].w * vf.w;
        p += __shfl_xor(p, 1);
        p += __shfl_xor(p, 2);
        p += __shfl_xor(p, 4);
        p += __shfl_xor(p, 8);
        p += __shfl_xor(p, 16);
        float q = __shfl_xor(p, 32);
        sc[2 * t]     = half ? q : p;
        sc[2 * t + 1] = half ? p : q;
    }

    float m = sc[0];
#pragma unroll
    for (int i = 1; i < NGROUPS; ++i) m = fmaxf(m, sc[i]);
    float w[12];
    float sum = 0.0f;
#pragma unroll
    for (int i = 0; i < NGROUPS; ++i) {
        w[i] = __expf(sc[i] - m);
        sum += w[i];
    }
    const float inv = 1.0f / sum;
#pragma unroll
    for (int i = 0; i < NGROUPS; ++i) w[i] *= inv;

    float4 acc = make_float4(0.f, 0.f, 0.f, 0.f);
#pragma unroll
    for (int t = 0; t < 6; ++t) {
        const float wt = w[2 * t + half];
        acc.x += wt * g[t].x;
        acc.y += wt * g[t].y;
        acc.z += wt * g[t].z;
        acc.w += wt * g[t].w;
    }
    acc.x += __shfl_xor(acc.x, 32);
    acc.y += __shfl_xor(acc.y, 32);
    acc.z += __shfl_xor(acc.z, 32);
    acc.w += __shfl_xor(acc.w, 32);

    if (lane < 32) {
        *reinterpret_cast<float4*>(out_weighted + (size_t)row * GDIM + l32 * 4) = acc;
    } else if (lane < 32 + NGROUPS) {
        out_weights[(size_t)row * NGROUPS + (lane - 32)] = w[lane - 32];
    }
}

extern "C" void kernel_launch(void* const* d_in, const int* in_sizes, int n_in,
                              void* d_out, int out_size, void* d_ws, size_t ws_size,
                              hipStream_t stream) {
    // Inputs: 0 robot_states (unused) 1 group_embeddings 2 Wr (unused)
    // 3 br (unused) 4 Wg 5 bg (unused) 6 Wa 7 ba (unused)
    const float* ge = (const float*)d_in[1];
    const float* Wg = (const float*)d_in[4];
    const float* Wa = (const float*)d_in[6];

    float* out_weighted = (float*)d_out;                       // ROWS*128
    float* out_weights  = out_weighted + (size_t)ROWS * GDIM;  // ROWS*12

    group_attn_fused<<<NBLOCKS, TPB, 0, stream>>>(
        ge, Wg, Wa, out_weighted, out_weights);
}